// Round 5
// baseline (2424.196 us; speedup 1.0000x reference)
//
#include <hip/hip_runtime.h>

constexpr int S   = 4096;
constexpr int D   = 64;
constexpr int NK  = 12;      // log2(4096) gathered positions
constexpr int TPB = 256;
constexpr int RPB = TPB / 4; // 64 rows per block (quad-per-row)
constexpr int BH  = 32;
constexpr long long CTX_ELEMS = (long long)BH * S * D;   // 8388608 floats

// inds[k] = S - (S >> k) = [0,2048,3072,3584,3840,3968,4032,4064,4080,4088,4092,4094]
__device__ __forceinline__ int log_ind(int k) { return S - (S >> k); }

__global__ __launch_bounds__(TPB, 6)
void logtrans_kernel(const float* __restrict__ Qg,
                     const float* __restrict__ Kg,
                     const float* __restrict__ Vg,
                     const int*   __restrict__ maskg,
                     float*       __restrict__ out_ctx,
                     float*       __restrict__ out_attn)
{
    __shared__ float4 kls[NK * 16];   // 3 KB
    __shared__ float4 vls[NK * 16];   // 3 KB

    const int t    = threadIdx.x;
    const int l    = t & 3;           // lane within quad
    const int rq   = t >> 2;          // row within block, 0..63
    const int row0 = blockIdx.x * RPB;
    const int r    = row0 + rq;       // global row
    const int bh   = r >> 12;
    const long long kvbase = (long long)bh * (S * D);

    // ---- stage gathered K/V rows (float4-coalesced, 384 float4s)
    for (int e = t; e < 2 * NK * 16; e += TPB) {
        const int mKV = e >= NK * 16;
        const int i   = mKV ? e - NK * 16 : e;
        const int k   = i >> 4;
        const int d4  = i & 15;
        const float4 v = *(const float4*)((mKV ? Vg : Kg) + kvbase
                                          + (long long)log_ind(k) * D + d4 * 4);
        (mKV ? vls : kls)[i] = v;
    }

    // ---- Q: lane l holds float4s {l+4j} of its row -> per instr a wave
    // covers 16 rows x 64 contiguous bytes = 16 full lines (line-perfect)
    float4 q4[4];
    const float4* qrow = (const float4*)(Qg + (long long)r * D);
    #pragma unroll
    for (int j = 0; j < 4; ++j) q4[j] = qrow[l + 4 * j];

    // ---- mask: lane l loads cols ind(l+4m), m=0..2; or-reduce 12-bit word
    unsigned mb = 0;
    const long long mbase = (long long)r * S;
    #pragma unroll
    for (int m = 0; m < 3; ++m) {
        const int k = l + 4 * m;
        if (maskg[mbase + log_ind(k)] != 0) mb |= (1u << k);
    }
    mb |= __shfl_xor(mb, 1);
    mb |= __shfl_xor(mb, 2);

    __syncthreads();

    // ---- scores: partial dot over this lane's 16 elems, quad butterfly reduce
    float sc[NK];
    #pragma unroll
    for (int k = 0; k < NK; ++k) {
        const float4* kp = kls + k * 16;
        float p = 0.f;
        #pragma unroll
        for (int j = 0; j < 4; ++j) {
            float4 kv = kp[l + 4 * j];
            p += q4[j].x * kv.x + q4[j].y * kv.y + q4[j].z * kv.z + q4[j].w * kv.w;
        }
        p += __shfl_xor(p, 1);
        p += __shfl_xor(p, 2);
        sc[k] = ((mb >> k) & 1u) ? -1.0e9f : p * 0.125f;
    }

    // ---- softmax over 12 (redundant in all 4 lanes of the quad)
    float m = sc[0];
    #pragma unroll
    for (int k = 1; k < NK; ++k) m = fmaxf(m, sc[k]);
    float sum = 0.f;
    #pragma unroll
    for (int k = 0; k < NK; ++k) { sc[k] = __expf(sc[k] - m); sum += sc[k]; }
    const float inv = 1.0f / sum;
    #pragma unroll
    for (int k = 0; k < NK; ++k) sc[k] *= inv;

    // ---- attn out: lanes l<3 each store one float4 -> one fully-contiguous
    // 768B-per-wave store instruction
    if (l < 3) {
        float4 av;
        av.x = sc[4*l+0]; av.y = sc[4*l+1]; av.z = sc[4*l+2]; av.w = sc[4*l+3];
        ((float4*)(out_attn + (long long)r * NK))[l] = av;
    }

    // ---- context = attn . V_g, lane l owns float4s {l+4j}
    float4* crow = (float4*)(out_ctx + (long long)r * D);
    #pragma unroll
    for (int j = 0; j < 4; ++j) {
        float4 acc; acc.x = acc.y = acc.z = acc.w = 0.f;
        #pragma unroll
        for (int k = 0; k < NK; ++k) {
            float4 vv = vls[k * 16 + l + 4 * j];
            acc.x += sc[k] * vv.x; acc.y += sc[k] * vv.y;
            acc.z += sc[k] * vv.z; acc.w += sc[k] * vv.w;
        }
        crow[l + 4 * j] = acc;   // per instr: 16 full lines, line-perfect
    }
}

extern "C" void kernel_launch(void* const* d_in, const int* in_sizes, int n_in,
                              void* d_out, int out_size, void* d_ws, size_t ws_size,
                              hipStream_t stream) {
    const float* Q    = (const float*)d_in[0];
    const float* K    = (const float*)d_in[1];
    const float* V    = (const float*)d_in[2];
    const int*   mask = (const int*)d_in[3];
    float* out_ctx  = (float*)d_out;
    float* out_attn = out_ctx + CTX_ELEMS;

    const int total_rows = BH * S;              // 131072
    logtrans_kernel<<<dim3(total_rows / RPB), dim3(TPB), 0, stream>>>(
        Q, K, V, mask, out_ctx, out_attn);
}